// Round 1
// baseline (123.145 us; speedup 1.0000x reference)
//
#include <hip/hip_runtime.h>

typedef unsigned int u32;

// Only the low 16 bits of every hash product matter (final % 65536, XOR is
// bitwise, mul distributes over mod 2^16) -> use masked primes + __umul24.
__device__ constexpr u32 BASEP[16] = {
    2654435761u, 2246822519u, 3266489917u, 2028178513u,
    1220703125u, 1610612741u,  805306457u,  402653189u,
    3674653429u, 2860486313u, 1073676287u, 2971215073u,
    1500450271u, 3267000013u, 2654435789u, 4049292737u};
__device__ constexpr u32 EXTP[16] = {   // EXT32[16..31]
    2246822531u, 3266489927u, 2028178519u, 1220703133u,
    1610612759u,  805306463u,  402653201u, 3674653441u,
    2860486319u, 1073676311u, 2971215091u, 1500450277u,
    3267000023u, 2654435801u, 4049292751u, 2246822537u};

#define TDIM 4096
#define TILE 256
#define HALO 128

__global__ __launch_bounds__(256) void rhp_kernel(
        const int* __restrict__ tokens, const float* __restrict__ tables,
        const float* __restrict__ Wc, float* __restrict__ out)
{
    __shared__ u32 toks[HALO + TILE];
    const int tid = threadIdx.x;
    const int g0  = blockIdx.x * TILE;     // flat position index of tile start
    const int t0  = g0 & (TDIM - 1);       // tiles never straddle a batch row

    for (int j = tid; j < HALO + TILE; j += TILE) {
        const int t = t0 - HALO + j;       // in-row index; <0 -> zero pad
        toks[j] = (t >= 0) ? (u32)tokens[g0 - HALO + j] : 0u;
    }
    __syncthreads();

    // ---- rolling hashes (255 terms; scales 0..4 share the BASE prefix) ----
    const int base = HALO + tid - 1;
    u32 h = 0u, k5 = 0u, k6 = 0u, k7 = 0u;
    u32 k0 = 0u, k1 = 0u, k2 = 0u, k3 = 0u;
#pragma unroll
    for (int i = 0; i < 16; ++i) {
        const u32 tv = toks[base - i];
        h  ^= __umul24(tv, BASEP[i] & 0xFFFFu);
        if (i == 0) k0 = h;
        if (i == 1) k1 = h;
        if (i == 3) k2 = h;
        if (i == 7) k3 = h;
        k5 ^= __umul24(tv, (BASEP[i]     ^ 0xDEADBEEFu) & 0xFFFFu);
        k6 ^= __umul24(tv, (BASEP[i & 7] ^ 0xCAFEBABEu) & 0xFFFFu);
        k7 ^= __umul24(tv, (BASEP[i & 7] ^ 0x8BADF00Du) & 0xFFFFu);
    }
    const u32 k4 = h & 0xFFFFu;
#pragma unroll
    for (int i = 16; i < 32; ++i) {
        const u32 tv = toks[base - i];
        k5 ^= __umul24(tv, (EXTP[i - 16] ^ 0xDEADBEEFu) & 0xFFFFu);
        k6 ^= __umul24(tv, (BASEP[i & 7] ^ 0xCAFEBABEu) & 0xFFFFu);
        k7 ^= __umul24(tv, (BASEP[i & 7] ^ 0x8BADF00Du) & 0xFFFFu);
    }
#pragma unroll
    for (int i = 32; i < 64; ++i) {
        const u32 tv = toks[base - i];
        k6 ^= __umul24(tv, (BASEP[i & 7] ^ 0xCAFEBABEu) & 0xFFFFu);
        k7 ^= __umul24(tv, (BASEP[i & 7] ^ 0x8BADF00Du) & 0xFFFFu);
    }
#pragma unroll
    for (int i = 64; i < 128; ++i) {
        const u32 tv = toks[base - i];
        k7 ^= __umul24(tv, (BASEP[i & 7] ^ 0x8BADF00Du) & 0xFFFFu);
    }
    k0 &= 0xFFFFu; k1 &= 0xFFFFu; k2 &= 0xFFFFu; k3 &= 0xFFFFu;
    k5 &= 0xFFFFu; k6 &= 0xFFFFu; k7 &= 0xFFFFu;

    // ---- short gather: tables[s][k_s], 16 floats each (64B aligned rows) ----
    float4 sv[16];
    {
        const u32 kk[4] = {k0, k1, k2, k3};
#pragma unroll
        for (int s = 0; s < 4; ++s) {
            const float4* r = (const float4*)(tables + (u32)s * 1048576u + kk[s] * 16u);
#pragma unroll
            for (int q = 0; q < 4; ++q) sv[s * 4 + q] = r[q];
        }
    }

    // ---- logits: lg[j] = sum_c short[c] * Wc[j*64+c]  (Wc loads uniform) ----
    float lg[8] = {0.f, 0.f, 0.f, 0.f, 0.f, 0.f, 0.f, 0.f};
    const float* svf = (const float*)&sv[0];
#pragma unroll
    for (int c = 0; c < 64; ++c) {
        const float v = svf[c];
#pragma unroll
        for (int j = 0; j < 8; ++j) lg[j] = fmaf(v, Wc[j * 64 + c], lg[j]);
    }

    u32 ck = 0u;
#pragma unroll
    for (int j = 0; j < 8; ++j)
        if (lg[j] > 0.0f) ck ^= (BASEP[j] & 0xFFFFu);   // low 16 bits suffice

    // ---- write short half of the 128-float output row ----
    float4* op = (float4*)(out + (size_t)(g0 + tid) * 128u);
#pragma unroll
    for (int q = 0; q < 16; ++q) op[q] = sv[q];

    // ---- long gather (scales 4..7 with cond-key XOR) + write ----
    const u32 lk[4] = {(k4 ^ ck) & 0xFFFFu, (k5 ^ ck) & 0xFFFFu,
                       (k6 ^ ck) & 0xFFFFu, (k7 ^ ck) & 0xFFFFu};
#pragma unroll
    for (int s = 0; s < 4; ++s) {
        const float4* r = (const float4*)(tables + (u32)(s + 4) * 1048576u + lk[s] * 16u);
        const float4 a = r[0], b = r[1], c = r[2], d = r[3];
        op[16 + s * 4 + 0] = a;
        op[16 + s * 4 + 1] = b;
        op[16 + s * 4 + 2] = c;
        op[16 + s * 4 + 3] = d;
    }
}

extern "C" void kernel_launch(void* const* d_in, const int* in_sizes, int n_in,
                              void* d_out, int out_size, void* d_ws, size_t ws_size,
                              hipStream_t stream) {
    const int*   tokens = (const int*)d_in[0];
    const float* tables = (const float*)d_in[1];
    const float* Wc     = (const float*)d_in[2];
    float*       out    = (float*)d_out;

    const int n_pos = in_sizes[0];             // B*T = 131072
    const int blocks = n_pos / TILE;           // 512
    hipLaunchKernelGGL(rhp_kernel, dim3(blocks), dim3(TILE), 0, stream,
                       tokens, tables, Wc, out);
}

// Round 2
// 120.415 us; speedup vs baseline: 1.0227x; 1.0227x over previous
//
#include <hip/hip_runtime.h>

typedef unsigned int u32;

// Only the low 16 bits of every hash product matter (final % 65536, XOR is
// bitwise, mul distributes over mod 2^16) -> use masked primes + __umul24.
__device__ constexpr u32 BASEP[16] = {
    2654435761u, 2246822519u, 3266489917u, 2028178513u,
    1220703125u, 1610612741u,  805306457u,  402653189u,
    3674653429u, 2860486313u, 1073676287u, 2971215073u,
    1500450271u, 3267000013u, 2654435789u, 4049292737u};
__device__ constexpr u32 EXTP[16] = {   // EXT32[16..31]
    2246822531u, 3266489927u, 2028178519u, 1220703133u,
    1610612759u,  805306463u,  402653201u, 3674653441u,
    2860486319u, 1073676311u, 2971215091u, 1500450277u,
    3267000023u, 2654435801u, 4049292751u, 2246822537u};

#define TDIM 4096
#define TILE 256
#define HALO 128

// ---------------- K1: rolling hashes -> packed keys in d_ws -----------------
// One thread per position. Writes uint4 per position:
//   word s = k_s | (k_{s+4} << 16),  s = 0..3
__global__ __launch_bounds__(256) void rhp_hash_kernel(
        const int* __restrict__ tokens, u32* __restrict__ keys)
{
    __shared__ u32 toks[HALO + TILE];
    const int tid = threadIdx.x;
    const int g0  = blockIdx.x * TILE;     // flat position index of tile start
    const int t0  = g0 & (TDIM - 1);       // tiles never straddle a batch row

    for (int j = tid; j < HALO + TILE; j += TILE) {
        const int t = t0 - HALO + j;       // in-row index; <0 -> zero pad
        toks[j] = (t >= 0) ? (u32)tokens[g0 - HALO + j] : 0u;
    }
    __syncthreads();

    const int base = HALO + tid - 1;
    u32 h = 0u, k5 = 0u, k6 = 0u, k7 = 0u;
    u32 k0 = 0u, k1 = 0u, k2 = 0u, k3 = 0u;
#pragma unroll
    for (int i = 0; i < 16; ++i) {
        const u32 tv = toks[base - i];
        h  ^= __umul24(tv, BASEP[i] & 0xFFFFu);
        if (i == 0) k0 = h;
        if (i == 1) k1 = h;
        if (i == 3) k2 = h;
        if (i == 7) k3 = h;
        k5 ^= __umul24(tv, (BASEP[i]     ^ 0xDEADBEEFu) & 0xFFFFu);
        k6 ^= __umul24(tv, (BASEP[i & 7] ^ 0xCAFEBABEu) & 0xFFFFu);
        k7 ^= __umul24(tv, (BASEP[i & 7] ^ 0x8BADF00Du) & 0xFFFFu);
    }
    const u32 k4 = h & 0xFFFFu;
#pragma unroll
    for (int i = 16; i < 32; ++i) {
        const u32 tv = toks[base - i];
        k5 ^= __umul24(tv, (EXTP[i - 16] ^ 0xDEADBEEFu) & 0xFFFFu);
        k6 ^= __umul24(tv, (BASEP[i & 7] ^ 0xCAFEBABEu) & 0xFFFFu);
        k7 ^= __umul24(tv, (BASEP[i & 7] ^ 0x8BADF00Du) & 0xFFFFu);
    }
#pragma unroll
    for (int i = 32; i < 64; ++i) {
        const u32 tv = toks[base - i];
        k6 ^= __umul24(tv, (BASEP[i & 7] ^ 0xCAFEBABEu) & 0xFFFFu);
        k7 ^= __umul24(tv, (BASEP[i & 7] ^ 0x8BADF00Du) & 0xFFFFu);
    }
#pragma unroll
    for (int i = 64; i < 128; ++i) {
        const u32 tv = toks[base - i];
        k7 ^= __umul24(tv, (BASEP[i & 7] ^ 0x8BADF00Du) & 0xFFFFu);
    }
    k0 &= 0xFFFFu; k1 &= 0xFFFFu; k2 &= 0xFFFFu; k3 &= 0xFFFFu;
    k5 &= 0xFFFFu; k6 &= 0xFFFFu; k7 &= 0xFFFFu;

    uint4 p;
    p.x = k0 | (k4 << 16);
    p.y = k1 | (k5 << 16);
    p.z = k2 | (k6 << 16);
    p.w = k3 | (k7 << 16);
    ((uint4*)keys)[g0 + tid] = p;
}

// ---------------- K2: gathers + logits + cond-key + output ------------------
// 4 threads per position (lane quad), one scale-pair (s, s+4) per thread.
// 524288 threads = 8192 waves -> 100% occupancy ceiling.
__global__ __launch_bounds__(256) void rhp_gather_kernel(
        const u32* __restrict__ keys, const float* __restrict__ tables,
        const float* __restrict__ Wc, float* __restrict__ out)
{
    __shared__ float wc_s[512];            // 8 x 64
    const int tid = threadIdx.x;
    if (tid < 128) ((float4*)wc_s)[tid] = ((const float4*)Wc)[tid];
    __syncthreads();

    const int s   = tid & 3;
    const int pos = blockIdx.x * 64 + (tid >> 2);

    const u32 kp  = keys[pos * 4 + s];     // coalesced: addr = tid*4 + blockbase
    const u32 ks  = kp & 0xFFFFu;

    // ---- short gather: tables[s][ks], 16 floats ----
    const float4* r = (const float4*)(tables + (u32)s * 1048576u + ks * 16u);
    float4 sv0 = r[0], sv1 = r[1], sv2 = r[2], sv3 = r[3];

    // ---- write short half (scale s occupies floats [s*16, s*16+16)) ----
    float4* op = (float4*)(out + (size_t)pos * 128u + (u32)s * 16u);
    op[0] = sv0; op[1] = sv1; op[2] = sv2; op[3] = sv3;

    // ---- partial logits over this thread's 16 columns (c = s*16 + i) ----
    float lg[8];
    const float4* w4 = (const float4*)wc_s; // index (j*64 + s*16 + q*4)/4
#pragma unroll
    for (int j = 0; j < 8; ++j) {
        const int b = j * 16 + s * 4;
        float4 w0 = w4[b + 0], w1 = w4[b + 1], w2 = w4[b + 2], w3 = w4[b + 3];
        float acc;
        acc = fmaf(sv0.x, w0.x, sv0.y * w0.y);
        acc = fmaf(sv0.z, w0.z, fmaf(sv0.w, w0.w, acc));
        acc = fmaf(sv1.x, w1.x, fmaf(sv1.y, w1.y, acc));
        acc = fmaf(sv1.z, w1.z, fmaf(sv1.w, w1.w, acc));
        acc = fmaf(sv2.x, w2.x, fmaf(sv2.y, w2.y, acc));
        acc = fmaf(sv2.z, w2.z, fmaf(sv2.w, w2.w, acc));
        acc = fmaf(sv3.x, w3.x, fmaf(sv3.y, w3.y, acc));
        acc = fmaf(sv3.z, w3.z, fmaf(sv3.w, w3.w, acc));
        lg[j] = acc;
    }
    // ---- reduce partials across the quad (lanes s=0..3) ----
#pragma unroll
    for (int j = 0; j < 8; ++j) {
        lg[j] += __shfl_xor(lg[j], 1);
        lg[j] += __shfl_xor(lg[j], 2);
    }

    u32 ck = 0u;
#pragma unroll
    for (int j = 0; j < 8; ++j)
        if (lg[j] > 0.0f) ck ^= (BASEP[j] & 0xFFFFu);   // low 16 bits suffice

    // ---- long gather: tables[s+4][(k_{s+4} ^ ck) % 65536] ----
    const u32 kl = ((kp >> 16) ^ ck) & 0xFFFFu;
    const float4* rl = (const float4*)(tables + (u32)(s + 4) * 1048576u + kl * 16u);
    float4 lv0 = rl[0], lv1 = rl[1], lv2 = rl[2], lv3 = rl[3];

    // long half: scale s+4 occupies floats [64 + s*16, 64 + s*16 + 16)
    float4* ol = (float4*)(out + (size_t)pos * 128u + 64u + (u32)s * 16u);
    ol[0] = lv0; ol[1] = lv1; ol[2] = lv2; ol[3] = lv3;
}

extern "C" void kernel_launch(void* const* d_in, const int* in_sizes, int n_in,
                              void* d_out, int out_size, void* d_ws, size_t ws_size,
                              hipStream_t stream) {
    const int*   tokens = (const int*)d_in[0];
    const float* tables = (const float*)d_in[1];
    const float* Wc     = (const float*)d_in[2];
    float*       out    = (float*)d_out;
    u32*         keys   = (u32*)d_ws;          // 131072 * 16 B = 2 MiB

    const int n_pos = in_sizes[0];             // B*T = 131072
    hipLaunchKernelGGL(rhp_hash_kernel, dim3(n_pos / TILE), dim3(TILE), 0, stream,
                       tokens, keys);
    hipLaunchKernelGGL(rhp_gather_kernel, dim3(n_pos / 64), dim3(256), 0, stream,
                       keys, tables, Wc, out);
}

// Round 3
// 109.956 us; speedup vs baseline: 1.1199x; 1.0951x over previous
//
#include <hip/hip_runtime.h>

typedef unsigned int u32;

// Only the low 16 bits of every hash product matter (final % 65536, XOR is
// bitwise, mul distributes over mod 2^16) -> masked primes + __umul24.
__device__ constexpr u32 BASEP[16] = {
    2654435761u, 2246822519u, 3266489917u, 2028178513u,
    1220703125u, 1610612741u,  805306457u,  402653189u,
    3674653429u, 2860486313u, 1073676287u, 2971215073u,
    1500450271u, 3267000013u, 2654435789u, 4049292737u};
__device__ constexpr u32 EXTP[16] = {   // EXT32[16..31]
    2246822531u, 3266489927u, 2028178519u, 1220703133u,
    1610612759u,  805306463u,  402653201u, 3674653441u,
    2860486319u, 1073676311u, 2971215091u, 1500450277u,
    3267000023u, 2654435801u, 4049292751u, 2246822537u};

#define TDIM 4096
#define PPB  16          // positions per 256-thread block (16 lanes/position)
#define HALO 128

// One fused kernel. Thread = (p = tid>>4, r = tid&15); r doubles as
// (s = r>>2, q = r&3) for the gather phase: scale s, float4 q of the 64B row.
// Hash: 255 mul-xor terms split 16 ways (i = r + 16m), reduced with a packed
// 16-bit XOR butterfly (XOR distributes over bit fields).
__global__ __launch_bounds__(256) void rhp_fused(
        const int* __restrict__ tokens, const float* __restrict__ tables,
        const float* __restrict__ Wc, float* __restrict__ out)
{
    __shared__ u32   toks[HALO + PPB];   // 144 tokens (halo zero-padded)
    __shared__ float wc_s[512];          // 8 x 64
    __shared__ u32   bp16[16], ep16[16]; // masked primes

    const int tid = threadIdx.x;
    const int g0  = blockIdx.x * PPB;        // flat position of tile start
    const int t0  = g0 & (TDIM - 1);         // 16 | 4096 -> no row straddle

    if (tid < 16) { bp16[tid] = BASEP[tid] & 0xFFFFu;
                    ep16[tid] = EXTP[tid]  & 0xFFFFu; }
    if (tid < 128) ((float4*)wc_s)[tid] = ((const float4*)Wc)[tid];
    if (tid < HALO + PPB) {
        const int t = t0 - HALO + tid;       // in-row index; <0 -> zero pad
        toks[tid] = (t >= 0) ? (u32)tokens[g0 - HALO + tid] : 0u;
    }
    __syncthreads();

    const int r   = tid & 15;
    const int p   = tid >> 4;
    const int pos = g0 + p;
    const int s   = (tid >> 2) & 3;
    const int q   = tid & 3;

    // ---- hash partials: this thread covers term indices i = r + 16m ----
    const int base = HALO + p - 1 - r;       // min 112-112=0, max 142
    const u32 v0 = toks[base      ], v1 = toks[base -  16];
    const u32 v2 = toks[base -  32], v3 = toks[base -  48];
    const u32 v4 = toks[base -  64], v5 = toks[base -  80];
    const u32 v6 = toks[base -  96], v7 = toks[base - 112];

    const u32 pb  = bp16[r];                 // BASE[r] & 0xFFFF
    const u32 pb7 = bp16[r & 7];             // BASE[r&7] & 0xFFFF
    const u32 pe  = ep16[r];                 // EXT32[16+r] & 0xFFFF
    const u32 p7  = pb7 ^ 0xF00Du;           // ^0x8BADF00D (low 16)
    const u32 p6  = pb7 ^ 0xBABEu;           // ^0xCAFEBABE
    const u32 p5a = pb  ^ 0xBEEFu;           // ^0xDEADBEEF, i = r
    const u32 p5b = pe  ^ 0xBEEFu;           //              i = r+16

    u32 k7p = __umul24(v0, p7) ^ __umul24(v1, p7) ^ __umul24(v2, p7) ^
              __umul24(v3, p7) ^ __umul24(v4, p7) ^ __umul24(v5, p7) ^
              __umul24(v6, p7) ^ __umul24(v7, p7);
    u32 k6p = __umul24(v0, p6) ^ __umul24(v1, p6) ^
              __umul24(v2, p6) ^ __umul24(v3, p6);
    u32 k5p = __umul24(v0, p5a) ^ __umul24(v1, p5b);
    u32 k4p = __umul24(v0, pb);
    const u32 k3p = (r < 8) ? k4p : 0u;      // k0..k3 reuse k4's i=r term
    const u32 k2p = (r < 4) ? k4p : 0u;
    const u32 k1p = (r < 2) ? k4p : 0u;
    const u32 k0p = (r == 0) ? k4p : 0u;

    // pack short|long<<16 per scale-pair, butterfly-XOR over the 16 lanes
    u32 P0 = (k0p & 0xFFFFu) | ((k4p & 0xFFFFu) << 16);
    u32 P1 = (k1p & 0xFFFFu) | ((k5p & 0xFFFFu) << 16);
    u32 P2 = (k2p & 0xFFFFu) | ((k6p & 0xFFFFu) << 16);
    u32 P3 = (k3p & 0xFFFFu) | ((k7p & 0xFFFFu) << 16);
#pragma unroll
    for (int d = 1; d <= 8; d <<= 1) {
        P0 ^= __shfl_xor(P0, d);
        P1 ^= __shfl_xor(P1, d);
        P2 ^= __shfl_xor(P2, d);
        P3 ^= __shfl_xor(P3, d);
    }
    const u32 Ps = (s == 0) ? P0 : (s == 1) ? P1 : (s == 2) ? P2 : P3;
    const u32 ks = Ps & 0xFFFFu;

    // ---- short gather: quad-coalesced 64B row (4 lanes x float4) ----
    const float4 sv = *(const float4*)(tables + (u32)s * 1048576u
                                       + ks * 16u + (u32)q * 4u);
    *(float4*)(out + (size_t)pos * 128u + (u32)s * 16u + (u32)q * 4u) = sv;

    // ---- partial logits over this lane's 4 columns (c = s*16 + q*4 + u) ----
    float lg[8];
#pragma unroll
    for (int j = 0; j < 8; ++j) {
        const float4 w = ((const float4*)wc_s)[j * 16 + s * 4 + q];
        lg[j] = fmaf(sv.x, w.x, fmaf(sv.y, w.y, fmaf(sv.z, w.z, sv.w * w.w)));
    }
#pragma unroll
    for (int d = 1; d <= 8; d <<= 1) {
#pragma unroll
        for (int j = 0; j < 8; ++j) lg[j] += __shfl_xor(lg[j], d);
    }

    u32 ck = 0u;
#pragma unroll
    for (int j = 0; j < 8; ++j)
        if (lg[j] > 0.0f) ck ^= (BASEP[j] & 0xFFFFu);  // low 16 bits suffice

    // ---- long gather: tables[s+4][(k_{s+4} ^ ck) % 65536] ----
    const u32 kl = ((Ps >> 16) ^ ck) & 0xFFFFu;
    const float4 lv = *(const float4*)(tables + (u32)(s + 4) * 1048576u
                                       + kl * 16u + (u32)q * 4u);
    *(float4*)(out + (size_t)pos * 128u + 64u + (u32)s * 16u + (u32)q * 4u) = lv;
}

extern "C" void kernel_launch(void* const* d_in, const int* in_sizes, int n_in,
                              void* d_out, int out_size, void* d_ws, size_t ws_size,
                              hipStream_t stream) {
    const int*   tokens = (const int*)d_in[0];
    const float* tables = (const float*)d_in[1];
    const float* Wc     = (const float*)d_in[2];
    float*       out    = (float*)d_out;

    const int n_pos = in_sizes[0];             // B*T = 131072
    hipLaunchKernelGGL(rhp_fused, dim3(n_pos / PPB), dim3(256), 0, stream,
                       tokens, tables, Wc, out);
}